// Round 5
// baseline (1600.700 us; speedup 1.0000x reference)
//
#include <hip/hip_runtime.h>

// Problem constants (reference: T=4096, N_ENVS=2048, fp32)
#define TT    4096
#define NENV  2048
#define N2    (NENV / 2)          // 1024 float2 columns
#define L     8                   // timesteps per chunk
#define NCH   (TT / L)            // 512 chunks
#define BPC   4                   // blocks per chunk
#define NBLK  (NCH * BPC)         // 2048 blocks
#define NTHR  128                 // 2 waves/block; need 8 blk/CU, capacity >=12

#define GAMMA 0.99f
#define GL    (0.99f * 0.95f)

typedef float v2f __attribute__((ext_vector_type(2)));

// Device-scope sense-reversing grid barrier. All threads of all NBLK blocks
// must call. Safe because launch_bounds(128,6) caps VGPR ~85 -> >=12 blk/CU
// capacity while only 8 blk/CU co-residency is required (1.5x margin), LDS=0.
__device__ __forceinline__ void gbar(int* cnt, unsigned* gen) {
    __syncthreads();
    if (threadIdx.x == 0) {
        const unsigned g =
            __hip_atomic_load(gen, __ATOMIC_RELAXED, __HIP_MEMORY_SCOPE_AGENT);
        __threadfence();   // make this block's pre-barrier writes agent-visible
        if (__hip_atomic_fetch_add(cnt, 1, __ATOMIC_ACQ_REL,
                                   __HIP_MEMORY_SCOPE_AGENT) == NBLK - 1) {
            __hip_atomic_store(cnt, 0, __ATOMIC_RELAXED,
                               __HIP_MEMORY_SCOPE_AGENT);
            __hip_atomic_store(gen, g + 1, __ATOMIC_RELEASE,
                               __HIP_MEMORY_SCOPE_AGENT);
        } else {
            while (__hip_atomic_load(gen, __ATOMIC_ACQUIRE,
                                     __HIP_MEMORY_SCOPE_AGENT) == g)
                __builtin_amdgcn_s_sleep(8);
        }
        __threadfence();   // acquire side: invalidate L1 before remote reads
    }
    __syncthreads();
}

// One fused kernel:
//  phase 1: stream r,v,nv,dn once; per-chunk affine (A,B) -> wsA/wsB;
//           carry di[8] (f2 x2 tasks) + done-bitmask in registers.
//  phase 2: 2048 scan threads (blocks 0..15) do the full 512-deep serial
//           scan, overwriting wsB[c] in place with g entering chunk c.
//  phase 3: replay from registers; re-read only v (L3-hot); nt-store outputs.
__global__ __launch_bounds__(NTHR, 6) void gae_fused(
    const float2* __restrict__ rp,  const float2* __restrict__ vp,
    const float2* __restrict__ np,  const int2*   __restrict__ dp,
    float* __restrict__ wsA, float* __restrict__ wsB,
    float2* __restrict__ adv2, float2* __restrict__ ret2,
    int* __restrict__ bar_cnt, unsigned* __restrict__ bar_gen)
{
    const int bid   = (int)blockIdx.x;
    const int tid   = (int)threadIdx.x;
    const int chunk = bid >> 2;
    const int col0  = ((bid & 3) << 8) + tid;   // f2-col, task 0
    const int col1  = col0 + NTHR;              // f2-col, task 1
    const int base0 = chunk * (L * N2) + col0;
    const int base1 = chunk * (L * N2) + col1;

    // ---- Phase 1 ----
    v2f di0[L], di1[L];
    unsigned dm = 0u;   // bits: task0 -> (2i+e), task1 -> 16+(2i+e)
    float A0x = 1.f, A0y = 1.f, B0x = 0.f, B0y = 0.f;
    float A1x = 1.f, A1y = 1.f, B1x = 0.f, B1y = 0.f;

#define P1(rr, vv, nn, dd, DIexpr, Av, Bv, sh)                   \
    {                                                            \
        const float nd_ = (dd) ? 0.0f : 1.0f;                    \
        const float d_  = (rr) + GAMMA * (nn) * nd_ - (vv);      \
        const float c_  = GL * nd_;                              \
        DIexpr = d_;                                             \
        (Bv) = d_ + c_ * (Bv);                                   \
        (Av) = c_ * (Av);                                        \
        dm |= ((dd) ? 1u : 0u) << (sh);                          \
    }

#pragma unroll
    for (int i = L - 1; i >= 0; --i) {
        const int i0 = base0 + i * N2;
        const int i1 = base1 + i * N2;
        const float2 r0 = rp[i0], r1 = rp[i1];
        const float2 v0 = vp[i0], v1 = vp[i1];
        const float2 n0 = np[i0], n1 = np[i1];
        const int2   d0 = dp[i0], d1 = dp[i1];
        P1(r0.x, v0.x, n0.x, d0.x, di0[i].x, A0x, B0x, 2 * i + 0);
        P1(r0.y, v0.y, n0.y, d0.y, di0[i].y, A0y, B0y, 2 * i + 1);
        P1(r1.x, v1.x, n1.x, d1.x, di1[i].x, A1x, B1x, 16 + 2 * i + 0);
        P1(r1.y, v1.y, n1.y, d1.y, di1[i].y, A1y, B1y, 16 + 2 * i + 1);
    }
    ((float2*)wsA)[chunk * N2 + col0] = make_float2(A0x, A0y);
    ((float2*)wsA)[chunk * N2 + col1] = make_float2(A1x, A1y);
    ((float2*)wsB)[chunk * N2 + col0] = make_float2(B0x, B0y);
    ((float2*)wsB)[chunk * N2 + col1] = make_float2(B1x, B1y);

    gbar(bar_cnt, bar_gen);

    // ---- Phase 2: serial scan, one thread per scalar column ----
    {
        const int gtid = bid * NTHR + tid;      // blocks 0..15 cover 2048 cols
        if (gtid < NENV) {
            const float* __restrict__ As = wsA;
            float*       __restrict__ Bs = wsB;
            float g = 0.0f;
            for (int grp = 0; grp < NCH / 8; ++grp) {
                float a[8], b[8];
#pragma unroll
                for (int j = 0; j < 8; ++j) {
                    const int c = NCH - 1 - grp * 8 - j;
                    a[j] = As[c * NENV + gtid];
                    b[j] = Bs[c * NENV + gtid];
                }
#pragma unroll
                for (int j = 0; j < 8; ++j) {
                    const int c = NCH - 1 - grp * 8 - j;
                    Bs[c * NENV + gtid] = g;    // g entering chunk c
                    g = fmaf(a[j], g, b[j]);
                }
            }
        }
    }

    gbar(bar_cnt, bar_gen);

    // ---- Phase 3: replay from registers; only v re-read ----
    {
        const float2 g0 = ((const float2*)wsB)[chunk * N2 + col0];
        const float2 g1 = ((const float2*)wsB)[chunk * N2 + col1];
        float g0x = g0.x, g0y = g0.y, g1x = g1.x, g1y = g1.y;

#define P3(DI, VV, G, sh, AO, RO)                                \
    {                                                            \
        const float c_ = ((dm >> (sh)) & 1u) ? 0.0f : GL;        \
        (G)  = (DI) + c_ * (G);                                  \
        (AO) = (G);                                              \
        (RO) = (G) + (VV);                                       \
    }

#pragma unroll
        for (int i = L - 1; i >= 0; --i) {
            const int i0 = base0 + i * N2;
            const int i1 = base1 + i * N2;
            const float2 v0 = vp[i0], v1 = vp[i1];
            v2f a0, t0, a1, t1;
            P3(di0[i].x, v0.x, g0x, 2 * i + 0,      a0.x, t0.x);
            P3(di0[i].y, v0.y, g0y, 2 * i + 1,      a0.y, t0.y);
            P3(di1[i].x, v1.x, g1x, 16 + 2 * i + 0, a1.x, t1.x);
            P3(di1[i].y, v1.y, g1y, 16 + 2 * i + 1, a1.y, t1.y);
            __builtin_nontemporal_store(a0, (v2f*)&adv2[i0]);
            __builtin_nontemporal_store(t0, (v2f*)&ret2[i0]);
            __builtin_nontemporal_store(a1, (v2f*)&adv2[i1]);
            __builtin_nontemporal_store(t1, (v2f*)&ret2[i1]);
        }
    }
}

extern "C" void kernel_launch(void* const* d_in, const int* in_sizes, int n_in,
                              void* d_out, int out_size, void* d_ws, size_t ws_size,
                              hipStream_t stream) {
    const float2* rp = (const float2*)d_in[0];
    const float2* vp = (const float2*)d_in[1];
    const float2* np = (const float2*)d_in[2];
    const int2*   dp = (const int2*)d_in[3];

    float2* adv2 = (float2*)d_out;
    float2* ret2 = adv2 + (size_t)TT * N2;

    float* wsA = (float*)d_ws;                       // 4 MiB (chunk A)
    float* wsB = wsA + (size_t)NCH * NENV;           // 4 MiB (chunk B -> g-in)
    char*  barp = (char*)d_ws + ((size_t)8 << 20);   // barrier state after 8 MiB
    int*      bar_cnt = (int*)barp;
    unsigned* bar_gen = (unsigned*)(barp + 8);

    // Zero the barrier state each replay (stream-ordered, graph-capturable).
    hipMemsetAsync(barp, 0, 16, stream);

    gae_fused<<<NBLK, NTHR, 0, stream>>>(rp, vp, np, dp, wsA, wsB,
                                         adv2, ret2, bar_cnt, bar_gen);
}

// Round 6
// 203.239 us; speedup vs baseline: 7.8759x; 7.8759x over previous
//
#include <hip/hip_runtime.h>

// Problem constants (reference: T=4096, N_ENVS=2048, fp32)
#define TT    4096
#define NENV  2048
#define N2    (NENV / 2)          // 1024 float2 columns
#define L     8                   // timesteps per chunk
#define NCH   (TT / L)            // 512 chunks
#define BPC   4                   // blocks per chunk
#define NBLK  (NCH * BPC)         // 2048 blocks

#define GAMMA 0.99f
#define GL    (0.99f * 0.95f)

typedef float v2f __attribute__((ext_vector_type(2)));

// float -> bf16 (round-to-nearest-even), returned in low 16 bits
static __device__ __forceinline__ unsigned bf16_rne(float f) {
    const unsigned u = __float_as_uint(f);
    return (u + 0x7FFFu + ((u >> 16) & 1u)) >> 16;
}

#define STEP_AB(r_, v_, nv_, dn_, A_, B_)                    \
    {                                                        \
        const float nd = (dn_) ? 0.0f : 1.0f;                \
        const float di = (r_) + GAMMA * (nv_) * nd - (v_);   \
        const float c  = GL * nd;                            \
        (B_) = di + c * (B_);                                \
        (A_) = c * (A_);                                     \
    }

#define STEP_OUT(r_, v_, nv_, dn_, g_, adv_, ret_)           \
    {                                                        \
        const float nd = (dn_) ? 0.0f : 1.0f;                \
        const float di = (r_) + GAMMA * (nv_) * nd - (v_);   \
        (g_) = di + GL * nd * (g_);                          \
        (adv_) = (g_);                                       \
        (ret_) = (g_) + (v_);                                \
    }

// ---- k2 helpers: 16-chunk groups, descending chunk index ----
#define P2_PREFETCH(abuf, bbuf, grp_)                        \
    _Pragma("unroll")                                        \
    for (int j = 0; j < 16; ++j) {                           \
        const int c = NCH - 1 - (grp_) * 16 - j;             \
        abuf[j] = As[c * NENV + col];                        \
        bbuf[j] = Bs[c * NENV + col];                        \
    }

#define P2_PROCESS(abuf, bbuf, grp_)                         \
    _Pragma("unroll")                                        \
    for (int j = 0; j < 16; ++j) {                           \
        const int c = NCH - 1 - (grp_) * 16 - j;             \
        Bs[c * NENV + col] = g;   /* g entering chunk c */   \
        g = fmaf(abuf[j], g, bbuf[j]);                       \
    }

// ============ di-store path (needs ~25 MiB ws) ============
// k1s: per-chunk affine + store di (packed bf16x2/uint) + done-mask.
__global__ __launch_bounds__(256, 4) void gae_k1s(
    const float2* __restrict__ rp,  const float2* __restrict__ vp,
    const float2* __restrict__ np,  const int2*   __restrict__ dp,
    float2* __restrict__ wsA, float2* __restrict__ wsB,
    unsigned* __restrict__ dib, unsigned short* __restrict__ msk)
{
    const int chunk = (int)blockIdx.x >> 2;
    const int c2    = (((int)blockIdx.x & 3) << 8) | (int)threadIdx.x;
    const int base  = chunk * (L * N2) + c2;

    float Ax = 1.f, Ay = 1.f, Bx = 0.f, By = 0.f;
    unsigned m = 0u;
#pragma unroll
    for (int i = L - 1; i >= 0; --i) {
        const int idx   = base + i * N2;
        const float2 r  = rp[idx];
        const float2 v  = vp[idx];
        const float2 nv = np[idx];
        const int2   dn = dp[idx];
        // x lane
        const float ndx = dn.x ? 0.0f : 1.0f;
        const float dix = r.x + GAMMA * nv.x * ndx - v.x;
        const float cx  = GL * ndx;
        Bx = dix + cx * Bx;  Ax = cx * Ax;
        // y lane
        const float ndy = dn.y ? 0.0f : 1.0f;
        const float diy = r.y + GAMMA * nv.y * ndy - v.y;
        const float cy  = GL * ndy;
        By = diy + cy * By;  Ay = cy * Ay;

        dib[idx] = bf16_rne(dix) | (bf16_rne(diy) << 16);
        m |= (dn.x ? 1u : 0u) << (2 * i);
        m |= (dn.y ? 1u : 0u) << (2 * i + 1);
    }
    wsA[chunk * N2 + c2] = make_float2(Ax, Ay);
    wsB[chunk * N2 + c2] = make_float2(Bx, By);
    msk[chunk * N2 + c2] = (unsigned short)m;
}

// k3s: replay from stored bf16 di + mask; re-reads only v (+g).
__global__ __launch_bounds__(256, 4) void gae_k3s(
    const float2* __restrict__ vp,
    const unsigned* __restrict__ dib, const unsigned short* __restrict__ msk,
    const float2* __restrict__ gin,
    float2* __restrict__ adv2, float2* __restrict__ ret2)
{
    const int chunk = (int)blockIdx.x >> 2;
    const int c2    = (((int)blockIdx.x & 3) << 8) | (int)threadIdx.x;
    const int base  = chunk * (L * N2) + c2;

    const float2 g0 = gin[chunk * N2 + c2];
    const unsigned m = msk[chunk * N2 + c2];
    float gx = g0.x, gy = g0.y;
#pragma unroll
    for (int i = L - 1; i >= 0; --i) {
        const int idx = base + i * N2;
        const unsigned dw = dib[idx];
        const float dix = __uint_as_float(dw << 16);
        const float diy = __uint_as_float(dw & 0xFFFF0000u);
        const float2 v  = vp[idx];
        const float cx = ((m >> (2 * i)) & 1u) ? 0.0f : GL;
        const float cy = ((m >> (2 * i + 1)) & 1u) ? 0.0f : GL;
        gx = dix + cx * gx;
        gy = diy + cy * gy;
        v2f a; a.x = gx;       a.y = gy;
        v2f t; t.x = gx + v.x; t.y = gy + v.y;
        __builtin_nontemporal_store(a, (v2f*)&adv2[idx]);
        __builtin_nontemporal_store(t, (v2f*)&ret2[idx]);
    }
}

// ============ fallback path (R4, proven @209) ============
__global__ __launch_bounds__(256, 8) void gae_k1(
    const float2* __restrict__ rp,  const float2* __restrict__ vp,
    const float2* __restrict__ np,  const int2*   __restrict__ dp,
    float2* __restrict__ wsA, float2* __restrict__ wsB)
{
    const int chunk = (int)blockIdx.x >> 2;
    const int c2    = (((int)blockIdx.x & 3) << 8) | (int)threadIdx.x;
    const int base  = chunk * (L * N2) + c2;
    float Ax = 1.f, Ay = 1.f, Bx = 0.f, By = 0.f;
#pragma unroll
    for (int i = L - 1; i >= 0; --i) {
        const int idx   = base + i * N2;
        const float2 r  = rp[idx];
        const float2 v  = vp[idx];
        const float2 nv = np[idx];
        const int2   dn = dp[idx];
        STEP_AB(r.x, v.x, nv.x, dn.x, Ax, Bx);
        STEP_AB(r.y, v.y, nv.y, dn.y, Ay, By);
    }
    wsA[chunk * N2 + c2] = make_float2(Ax, Ay);
    wsB[chunk * N2 + c2] = make_float2(Bx, By);
}

__global__ __launch_bounds__(256, 8) void gae_k3(
    const float2* __restrict__ rp,  const float2* __restrict__ vp,
    const float2* __restrict__ np,  const int2*   __restrict__ dp,
    const float2* __restrict__ gin,
    float2* __restrict__ adv2, float2* __restrict__ ret2)
{
    const int chunk = (int)blockIdx.x >> 2;
    const int c2    = (((int)blockIdx.x & 3) << 8) | (int)threadIdx.x;
    const int base  = chunk * (L * N2) + c2;
    const float2 g0 = gin[chunk * N2 + c2];
    float gx = g0.x, gy = g0.y;
#pragma unroll
    for (int i = L - 1; i >= 0; --i) {
        const int idx   = base + i * N2;
        const float2 r  = rp[idx];
        const float2 v  = vp[idx];
        const float2 nv = np[idx];
        const int2   dn = dp[idx];
        float ax, ay, tx, ty;
        STEP_OUT(r.x, v.x, nv.x, dn.x, gx, ax, tx);
        STEP_OUT(r.y, v.y, nv.y, dn.y, gy, ay, ty);
        v2f av; av.x = ax; av.y = ay;
        v2f tv; tv.x = tx; tv.y = ty;
        __builtin_nontemporal_store(av, (v2f*)&adv2[idx]);
        __builtin_nontemporal_store(tv, (v2f*)&ret2[idx]);
    }
}

// ---- k2: full-depth serial scan over 512 chunk affines (shared, proven).
__global__ __launch_bounds__(64) void gae_k2(
    const float* __restrict__ As, float* __restrict__ Bs)
{
    const int col = (int)blockIdx.x * 64 + (int)threadIdx.x;   // 32 blocks
    float a0[16], b0[16], a1[16], b1[16];
    float g = 0.0f;
    P2_PREFETCH(a0, b0, 0)
    for (int grp = 0; grp < NCH / 16; grp += 2) {
        P2_PREFETCH(a1, b1, grp + 1)
        P2_PROCESS(a0, b0, grp)
        if (grp + 2 < NCH / 16) { P2_PREFETCH(a0, b0, grp + 2) }
        P2_PROCESS(a1, b1, grp + 1)
    }
}

extern "C" void kernel_launch(void* const* d_in, const int* in_sizes, int n_in,
                              void* d_out, int out_size, void* d_ws, size_t ws_size,
                              hipStream_t stream) {
    const float2* rp = (const float2*)d_in[0];
    const float2* vp = (const float2*)d_in[1];
    const float2* np = (const float2*)d_in[2];
    const int2*   dp = (const int2*)d_in[3];

    float2* adv2 = (float2*)d_out;
    float2* ret2 = adv2 + (size_t)TT * N2;

    float2* wsA = (float2*)d_ws;                       // 4 MiB (chunk A)
    float2* wsB = wsA + (size_t)NCH * N2;              // 4 MiB (chunk B -> g-in)

    const size_t need = ((size_t)8 << 20)              // wsA+wsB
                      + (size_t)TT * N2 * 4            // dib  16 MiB
                      + (size_t)NCH * N2 * 2;          // msk   1 MiB

    if (ws_size >= need) {
        unsigned*       dib = (unsigned*)((char*)d_ws + ((size_t)8 << 20));
        unsigned short* msk = (unsigned short*)(dib + (size_t)TT * N2);
        gae_k1s<<<NBLK, 256, 0, stream>>>(rp, vp, np, dp, wsA, wsB, dib, msk);
        gae_k2<<<NENV / 64, 64, 0, stream>>>((const float*)wsA, (float*)wsB);
        gae_k3s<<<NBLK, 256, 0, stream>>>(vp, dib, msk, wsB, adv2, ret2);
    } else {
        gae_k1<<<NBLK, 256, 0, stream>>>(rp, vp, np, dp, wsA, wsB);
        gae_k2<<<NENV / 64, 64, 0, stream>>>((const float*)wsA, (float*)wsB);
        gae_k3<<<NBLK, 256, 0, stream>>>(rp, vp, np, dp, wsB, adv2, ret2);
    }
}